// Round 6
// baseline (372.961 us; speedup 1.0000x reference)
//
#include <hip/hip_runtime.h>
#include <math.h>

#define NN 10000
#define NE 160000
#define NG 64
#define DIM 32
#define CAP 96   // per-node edge slot capacity (max degree ~40 at Binomial(160K,1e-4))
#define NBIN (CAP + 1)
#define SROWS 320   // s2s LDS row cache capacity (~13 sigma above mean graph size)

typedef __attribute__((ext_vector_type(8))) short bf16x8;
typedef __attribute__((ext_vector_type(4))) float f32x4;
typedef __attribute__((ext_vector_type(2))) float f32x2;

__device__ __forceinline__ float sigmoidf_(float x) { return 1.f / (1.f + expf(-x)); }

// round-to-nearest-even fp32 -> bf16 bits
__device__ __forceinline__ unsigned short f2bf(float x) {
    unsigned u = __float_as_uint(x);
    u += 0x7FFF + ((u >> 16) & 1);
    return (unsigned short)(u >> 16);
}
__device__ __forceinline__ float bf2f(unsigned short b) {
    return __uint_as_float(((unsigned)b) << 16);
}
__device__ __forceinline__ float rlanef(float v, int i) {
    return __uint_as_float((unsigned)__builtin_amdgcn_readlane((int)__float_as_uint(v), i));
}

// ---------------------------------------------------------------- fused setup + fill
//   b<128:        W2 -> B-fragment bf16 hi/lo planes (float4 reads, 4 elems/thread)
//                 h' = 2*(h&63)+(h>>6) permuted (matches conv's packed cvt stores)
//   b<441:        lin0 + relu (float4)
//   b==441:       gstart binary search
//   b>=442:       direct-slot edge bucketing (625 blocks) + Acnt degree-counting:
//                 #nodes with deg > d == #edges whose atomicAdd returned d, so the
//                 descending-sort bases come free (sub-banked x32 vs contention).
__global__ void k_setup(const float* __restrict__ w2, unsigned short* __restrict__ w2f,
                        const float* __restrict__ x, const float* __restrict__ lw,
                        const float* __restrict__ lb, float* __restrict__ out,
                        const int* __restrict__ batch, int* __restrict__ gstart,
                        const int* __restrict__ ei, const float* __restrict__ ea,
                        int* __restrict__ cursor, int* __restrict__ acnt,
                        int* __restrict__ srt_src, float* __restrict__ srt_ea) {
    int b = blockIdx.x, t = threadIdx.x;
    if (b < 128) {
        int base = (b * 256 + t) * 4;                 // linear w2 index (coalesced float4)
        float4 v4 = *(const float4*)(w2 + base);
        #pragma unroll
        for (int u = 0; u < 4; ++u) {
            int tid = base + u;
            int h = tid >> 10, rem = tid & 1023, i = rem >> 5, n = rem & 31;
            float v = ((const float*)&v4)[u];
            unsigned short hi = f2bf(v);
            unsigned short lo = f2bf(v - bf2f(hi));
            int hp = 2 * (h & 63) + (h >> 6);         // h' permutation
            int s = hp >> 5, hm = hp & 31, q = hm >> 3, j = hm & 7;
            int tile = n >> 4, nn = n & 15, lane = q * 16 + nn;
            int c = (i * 4 + s) * 2 + tile;
            w2f[(c * 2 + 0) * 512 + lane * 8 + j] = hi;
            w2f[(c * 2 + 1) * 512 + lane * 8 + j] = lo;
        }
    } else if (b < 441) {
        int idx4 = (b - 128) * 256 + t;               // float4 index into out
        if (idx4 < NN * DIM / 4) {
            int n = (idx4 * 4) >> 5, d0 = (idx4 * 4) & 31;
            float xv = x[n];
            float4 wv = *(const float4*)(lw + d0);
            float4 bv = *(const float4*)(lb + d0);
            float4 o;
            o.x = fmaxf(xv * wv.x + bv.x, 0.f);
            o.y = fmaxf(xv * wv.y + bv.y, 0.f);
            o.z = fmaxf(xv * wv.z + bv.z, 0.f);
            o.w = fmaxf(xv * wv.w + bv.w, 0.f);
            *(float4*)(out + idx4 * 4) = o;
        }
    } else if (b == 441) {
        if (t <= NG) {
            int g = t, lo = 0, hi = NN;
            while (lo < hi) { int mid = (lo + hi) >> 1; if (batch[mid] < g) lo = mid + 1; else hi = mid; }
            gstart[g] = lo;
        }
    } else {
        int e = (b - 442) * 256 + t;
        if (e < NE) {
            int d = ei[NE + e];
            int p = atomicAdd(&cursor[d], 1);
            int pos = d * CAP + p;
            srt_src[pos] = ei[e];
            *(float2*)(srt_ea + 2 * pos) = *(const float2*)(ea + 2 * e);
            int pc = p < CAP - 1 ? p : CAP - 1;
            atomicAdd(&acnt[pc * 32 + (t & 31)], 1);  // degree-count, sub-banked
        }
    }
}

// ---------------------------------------------------------------- perm scatter (wide)
// base[d] = #nodes with deg > d = sum_k acnt[d*32+k]. Nodes scattered into perm
// in DESCENDING degree order; equal-degree order arbitrary (atomic).
__global__ __launch_bounds__(256) void k_scatter(const int* __restrict__ cursor,
                                                 const int* __restrict__ acnt,
                                                 int* __restrict__ gcur,
                                                 int* __restrict__ perm) {
    __shared__ int sbase[NBIN];
    int t = threadIdx.x;
    if (t < NBIN) {
        int s = 0;
        if (t < CAP) {
            #pragma unroll
            for (int k = 0; k < 32; ++k) s += acnt[t * 32 + k];
        }
        sbase[t] = s;                                  // base[CAP] = 0
    }
    __syncthreads();
    int gt = blockIdx.x * 256 + t;
    for (int n = gt; n < NN; n += 40 * 256) {
        int d = cursor[n]; d = d > CAP ? CAP : d;
        int pos = sbase[d] + atomicAdd(&gcur[d], 1);
        perm[pos] = n;
    }
}

// ---------------------------------------------------------------- NNConv + GRU fused
// R2-verified structure (66.5us): 8 waves / 8 nodes / 512 thr; pk_fma f32x2 edge
// accumulation; h'-adjacent packed cvt stores; readlane-preloaded edge metadata;
// Sg through LDS. UNTOUCHED this round.
#define NS 1040
#define PS 8320
__global__ __launch_bounds__(512, 4) void k_conv_gru(
    const int* __restrict__ perm,
    const int* __restrict__ cursor, const int* __restrict__ srt_src,
    const float* __restrict__ srt_ea,
    const float* __restrict__ w1, const float* __restrict__ b1,
    const unsigned short* __restrict__ w2f, const float* __restrict__ b2,
    const float* __restrict__ out_old,
    const float* __restrict__ root, const float* __restrict__ cbias,
    const float* __restrict__ wih, const float* __restrict__ whh,
    const float* __restrict__ bih, const float* __restrict__ bhh,
    float* __restrict__ out_new)
{
    __shared__ __align__(16) unsigned short RB[2 * PS];   // hi plane + lo plane
    __shared__ float sSg[8][DIM];
    __shared__ int sNode[8];
    int t = threadIdx.x;
    int wave = t >> 6, lane = t & 63;
    int n0 = blockIdx.x * 8;
    int n = perm[n0 + wave];
    if (lane == 0) sNode[wave] = n;

    // ---------------- edge phase ----------------
    f32x2 acc2[32];                       // .x: h'=2*lane, .y: h'=2*lane+1
    #pragma unroll
    for (int i = 0; i < 32; ++i) acc2[i] = (f32x2){0.f, 0.f};
    float sacc = 0.f;

    float w1a0 = w1[lane],      w1c0 = w1[128 + lane],  bb0 = b1[lane];
    float w1a1 = w1[64 + lane], w1c1 = w1[192 + lane],  bb1 = b1[64 + lane];

    int deg = cursor[n];
    int rs = n * CAP;
    const float2* eap = (const float2*)srt_ea;

    int msrc = 0; float mex = 0.f, mey = 0.f;
    if (lane < deg) {
        msrc = srt_src[rs + lane];
        float2 a = eap[rs + lane];
        mex = a.x; mey = a.y;
    }

    int dmain = deg < 64 ? deg : 64;
    int i = 0;
    for (; i + 1 < dmain; i += 2) {
        int s0 = __builtin_amdgcn_readlane(msrc, i);
        int s1 = __builtin_amdgcn_readlane(msrc, i + 1);
        float a0x = rlanef(mex, i),     a0y = rlanef(mey, i);
        float a1x = rlanef(mex, i + 1), a1y = rlanef(mey, i + 1);
        const float* o0 = out_old + s0 * DIM;     // uniform -> s_load
        const float* o1 = out_old + s1 * DIM;     // independent chain
        f32x2 r0 = { fmaxf(a0x * w1a0 + a0y * w1c0 + bb0, 0.f),
                     fmaxf(a0x * w1a1 + a0y * w1c1 + bb1, 0.f) };
        f32x2 r1 = { fmaxf(a1x * w1a0 + a1y * w1c0 + bb0, 0.f),
                     fmaxf(a1x * w1a1 + a1y * w1c1 + bb1, 0.f) };
        #pragma unroll
        for (int q = 0; q < 32; ++q)
            acc2[q] += r0 * o0[q];                // v_pk_fma_f32
        #pragma unroll
        for (int q = 0; q < 32; ++q)
            acc2[q] += r1 * o1[q];
        const float* oc = (lane < 32) ? (o0 + lane) : (o1 + lane - 32);
        sacc += *oc;
    }
    if (i < dmain) {                               // tail edge
        int s0 = __builtin_amdgcn_readlane(msrc, i);
        float a0x = rlanef(mex, i), a0y = rlanef(mey, i);
        const float* o0 = out_old + s0 * DIM;
        f32x2 r0 = { fmaxf(a0x * w1a0 + a0y * w1c0 + bb0, 0.f),
                     fmaxf(a0x * w1a1 + a0y * w1c1 + bb1, 0.f) };
        #pragma unroll
        for (int q = 0; q < 32; ++q)
            acc2[q] += r0 * o0[q];
        if (lane < 32) sacc += o0[lane];
    }
    for (int p = rs + 64; p < rs + deg; ++p) {     // rare fallback deg > 64
        int s0 = __builtin_amdgcn_readfirstlane(srt_src[p]);
        float2 a0 = eap[p];
        const float* o0 = out_old + s0 * DIM;
        f32x2 r0 = { fmaxf(a0.x * w1a0 + a0.y * w1c0 + bb0, 0.f),
                     fmaxf(a0.x * w1a1 + a0.y * w1c1 + bb1, 0.f) };
        #pragma unroll
        for (int q = 0; q < 32; ++q)
            acc2[q] += r0 * o0[q];
        if (lane < 32) sacc += o0[lane];
    }
    sacc += __shfl_xor(sacc, 32);                  // combine the two row-halves
    if (lane < DIM) sSg[wave][lane] = sacc;

    // ---------------- MFMA contraction: 4 i-passes of 8 ----------------
    int quad = lane >> 4;
    int mm = lane & 7;                  // A rows 8..15 dup of 0..7 (unread in D)
    unsigned aoff = (unsigned)(mm * NS + wave * 128 + quad * 8);
    f32x4 acc0 = {0.f, 0.f, 0.f, 0.f};
    f32x4 acc1 = {0.f, 0.f, 0.f, 0.f};

    unsigned short* Hw = RB + wave * NS;
    unsigned short* Lw = RB + PS + wave * NS;

    #pragma unroll
    for (int pass = 0; pass < 4; ++pass) {
        if (pass) __syncthreads();                 // prior pass's reads done
        #pragma unroll
        for (int li = 0; li < 8; ++li) {
            f32x2 v = acc2[pass * 8 + li];         // h'=2*lane (.x), 2*lane+1 (.y)
            unsigned short h0 = f2bf(v.x);
            unsigned short l0 = f2bf(v.x - bf2f(h0));
            unsigned short h1 = f2bf(v.y);
            unsigned short l1 = f2bf(v.y - bf2f(h1));
            *(unsigned*)(Hw + li * 128 + 2 * lane) = (unsigned)h0 | ((unsigned)h1 << 16);
            *(unsigned*)(Lw + li * 128 + 2 * lane) = (unsigned)l0 | ((unsigned)l1 << 16);
        }
        __syncthreads();
        int ig = pass * 8 + wave;                  // global i-row this wave covers
        #pragma unroll
        for (int s = 0; s < 4; ++s) {
            bf16x8 ah = *(const bf16x8*)(RB + aoff + s * 32);
            bf16x8 al = *(const bf16x8*)(RB + PS + aoff + s * 32);
            const unsigned short* bp = w2f + (unsigned)((ig * 4 + s) * 2048 + lane * 8);
            bf16x8 bh0 = *(const bf16x8*)(bp);
            bf16x8 bl0 = *(const bf16x8*)(bp + 512);
            bf16x8 bh1 = *(const bf16x8*)(bp + 1024);
            bf16x8 bl1 = *(const bf16x8*)(bp + 1536);
            acc0 = __builtin_amdgcn_mfma_f32_16x16x32_bf16(ah, bh0, acc0, 0, 0, 0);
            acc0 = __builtin_amdgcn_mfma_f32_16x16x32_bf16(ah, bl0, acc0, 0, 0, 0);
            acc0 = __builtin_amdgcn_mfma_f32_16x16x32_bf16(al, bh0, acc0, 0, 0, 0);
            acc1 = __builtin_amdgcn_mfma_f32_16x16x32_bf16(ah, bh1, acc1, 0, 0, 0);
            acc1 = __builtin_amdgcn_mfma_f32_16x16x32_bf16(ah, bl1, acc1, 0, 0, 0);
            acc1 = __builtin_amdgcn_mfma_f32_16x16x32_bf16(al, bh1, acc1, 0, 0, 0);
        }
    }
    __syncthreads();                               // all RB reads complete

    // ---- K-partial reduction through LDS (reuse RB as float area) ----
    float* part = (float*)RB;                      // 16 tiles x 64 lanes x 4 = 16 KB
    #pragma unroll
    for (int r = 0; r < 4; ++r) {
        part[((wave * 2 + 0) * 64 + lane) * 4 + r] = acc0[r];
        part[((wave * 2 + 1) * 64 + lane) * 4 + r] = acc1[r];
    }
    __syncthreads();

    // ---------------- fused GRU epilogue (threads 0..255: 8 nodes x 32 dims) ----------------
    if (t < 256) {
        int nb = t >> 5, d = t & 31;
        int nn_ = sNode[nb];
        int base = t & 32;                          // shfl base within wave
        int tile = d >> 4, col = d & 15;
        int lidx = (nb >> 2) * 16 + col, reg = nb & 3;
        float aggv = 0.f;
        #pragma unroll
        for (int wv = 0; wv < 16; ++wv)
            aggv += part[((wv * 2 + tile) * 64 + lidx) * 4 + reg];

        float bt = 0.f;
        #pragma unroll 8
        for (int i2 = 0; i2 < DIM; ++i2) bt += sSg[nb][i2] * b2[i2 * DIM + d];
        int cdeg = cursor[nn_];
        float degf = (float)(cdeg > 0 ? cdeg : 1);
        aggv = (aggv + bt) / degf;

        float x = out_old[nn_ * DIM + d];           // h_old[d]
        float rootsum = 0.f;
        #pragma unroll 8
        for (int k = 0; k < DIM; ++k)
            rootsum += __shfl(x, base + k) * root[k * DIM + d];
        float m = fmaxf(aggv + rootsum + cbias[d], 0.f);

        float gir = bih[d], giz = bih[DIM + d], gin = bih[2 * DIM + d];
        float ghr = bhh[d], ghz = bhh[DIM + d], ghn = bhh[2 * DIM + d];
        #pragma unroll 4
        for (int k = 0; k < DIM; ++k) {
            float mk = __shfl(m, base + k);
            float hk = __shfl(x, base + k);
            gir += mk * wih[k * 96 + d];
            giz += mk * wih[k * 96 + DIM + d];
            gin += mk * wih[k * 96 + 2 * DIM + d];
            ghr += hk * whh[k * 96 + d];
            ghz += hk * whh[k * 96 + DIM + d];
            ghn += hk * whh[k * 96 + 2 * DIM + d];
        }
        float rg = sigmoidf_(gir + ghr);
        float zg = sigmoidf_(giz + ghz);
        float ng = tanhf(gin + rg * ghn);
        out_new[nn_ * DIM + d] = (1.f - zg) * ng + zg * x;
    }
}

// ---------------------------------------------------------------- Set2Set + head
// R6: graph rows staged in LDS ONCE (padded [.][33], conflict-free) instead of
// 9 global scans; softmax scratch in LDS (no ebuf traffic); weights read direct
// (L1-hot; the 48KB LDS preload cost more than it saved). Global fallback if
// a graph exceeds SROWS rows.
__global__ __launch_bounds__(256) void k_set2set(
    const float* __restrict__ out, const int* __restrict__ gstart,
    const float* __restrict__ wih, const float* __restrict__ whh,
    const float* __restrict__ bih, const float* __restrict__ bhh,
    const float* __restrict__ l1w, const float* __restrict__ l1b,
    const float* __restrict__ l2w, const float* __restrict__ l2b,
    float* __restrict__ ebuf, float* __restrict__ y)
{
    __shared__ float sX[SROWS][DIM + 1];   // 42.2 KB
    __shared__ float sA[SROWS];
    __shared__ float sq[2 * DIM];
    __shared__ float shh[DIM], scc[DIM];
    __shared__ float sgates[4 * DIM];
    __shared__ float sacc[8][DIM];
    __shared__ float sredA[4], sredB[4];

    int g = blockIdx.x, t = threadIdx.x;
    int ns = gstart[g], ne = gstart[g + 1];
    int cnt = ne - ns;
    bool staged = (cnt <= SROWS);
    if (staged) {
        const float4* src = (const float4*)(out + (size_t)ns * DIM);
        for (int i = t; i < cnt * 8; i += 256) {
            int r = i >> 3, c = i & 7;
            float4 v = src[i];
            sX[r][c * 4 + 0] = v.x; sX[r][c * 4 + 1] = v.y;
            sX[r][c * 4 + 2] = v.z; sX[r][c * 4 + 3] = v.w;
        }
    }
    if (t < 2 * DIM) sq[t] = 0.f;
    if (t < DIM) { shh[t] = 0.f; scc[t] = 0.f; }
    __syncthreads();

    for (int step = 0; step < 3; ++step) {
        if (t < 128) {
            float acc = bih[t] + bhh[t];
            #pragma unroll 8
            for (int k = 0; k < 2 * DIM; ++k) acc += sq[k] * wih[k * 128 + t];
            #pragma unroll 8
            for (int k = 0; k < DIM; ++k)     acc += shh[k] * whh[k * 128 + t];
            sgates[t] = acc;
        }
        __syncthreads();
        if (t < DIM) {
            float ig = sigmoidf_(sgates[t]);
            float fg = sigmoidf_(sgates[DIM + t]);
            float gg = tanhf(sgates[2 * DIM + t]);
            float og = sigmoidf_(sgates[3 * DIM + t]);
            float c_new = fg * scc[t] + ig * gg;
            float h_new = og * tanhf(c_new);
            scc[t] = c_new;
            shh[t] = h_new;
            sq[t] = h_new;
        }
        __syncthreads();

        float lmax = -3.0e38f;
        if (staged) {
            for (int r = t; r < cnt; r += 256) {
                float e = 0.f;
                #pragma unroll
                for (int q = 0; q < DIM; ++q) e += sX[r][q] * shh[q];
                sA[r] = e;
                lmax = fmaxf(lmax, e);
            }
        } else {
            for (int n = ns + t; n < ne; n += 256) {
                const float4* orow = (const float4*)(out + n * DIM);
                float e = 0.f;
                #pragma unroll
                for (int q = 0; q < 8; ++q) {
                    float4 o4 = orow[q];
                    e += o4.x * shh[4 * q] + o4.y * shh[4 * q + 1]
                       + o4.z * shh[4 * q + 2] + o4.w * shh[4 * q + 3];
                }
                ebuf[n] = e;
                lmax = fmaxf(lmax, e);
            }
        }
        #pragma unroll
        for (int s = 1; s < 64; s <<= 1) lmax = fmaxf(lmax, __shfl_xor(lmax, s));
        if ((t & 63) == 0) sredA[t >> 6] = lmax;
        __syncthreads();
        float M = fmaxf(fmaxf(sredA[0], sredA[1]), fmaxf(sredA[2], sredA[3]));

        float lsum = 0.f;
        if (staged) {
            for (int r = t; r < cnt; r += 256) {
                float v = expf(sA[r] - M);
                sA[r] = v;
                lsum += v;
            }
        } else {
            for (int n = ns + t; n < ne; n += 256) {
                float v = expf(ebuf[n] - M);
                ebuf[n] = v;
                lsum += v;
            }
        }
        #pragma unroll
        for (int s = 1; s < 64; s <<= 1) lsum += __shfl_xor(lsum, s);
        if ((t & 63) == 0) sredB[t >> 6] = lsum;
        __syncthreads();
        float S = sredB[0] + sredB[1] + sredB[2] + sredB[3];
        float inv = (S > 0.f) ? 1.f / S : 0.f;

        int stp = t >> 5, d = t & 31;
        float racc = 0.f;
        if (staged) {
            for (int r = stp; r < cnt; r += 8)
                racc += sA[r] * sX[r][d];
        } else {
            for (int n = ns + stp; n < ne; n += 8)
                racc += ebuf[n] * out[n * DIM + d];
        }
        sacc[stp][d] = racc;
        __syncthreads();
        if (t < DIM) {
            float r = 0.f;
            #pragma unroll
            for (int s = 0; s < 8; ++s) r += sacc[s][t];
            sq[DIM + t] = r * inv;
        }
        __syncthreads();
    }

    if (t < DIM) {
        float h = l1b[t];
        #pragma unroll 8
        for (int k = 0; k < 2 * DIM; ++k) h += sq[k] * l1w[k * DIM + t];
        float v = fmaxf(h, 0.f) * l2w[t];
        #pragma unroll
        for (int s = 1; s < 32; s <<= 1) v += __shfl_xor(v, s);
        if (t == 0) y[g] = v + l2b[0];
    }
}

// ---------------------------------------------------------------- launch
extern "C" void kernel_launch(void* const* d_in, const int* in_sizes, int n_in,
                              void* d_out, int out_size, void* d_ws, size_t ws_size,
                              hipStream_t stream) {
    const float* x         = (const float*)d_in[0];
    const float* edge_attr = (const float*)d_in[1];
    const float* lin0_w    = (const float*)d_in[2];
    const float* lin0_b    = (const float*)d_in[3];
    const float* nn_w1     = (const float*)d_in[4];
    const float* nn_b1     = (const float*)d_in[5];
    const float* nn_w2     = (const float*)d_in[6];
    const float* nn_b2     = (const float*)d_in[7];
    const float* conv_root = (const float*)d_in[8];
    const float* conv_bias = (const float*)d_in[9];
    const float* gru_w_ih  = (const float*)d_in[10];
    const float* gru_w_hh  = (const float*)d_in[11];
    const float* gru_b_ih  = (const float*)d_in[12];
    const float* gru_b_hh  = (const float*)d_in[13];
    const float* lstm_w_ih = (const float*)d_in[14];
    const float* lstm_w_hh = (const float*)d_in[15];
    const float* lstm_b_ih = (const float*)d_in[16];
    const float* lstm_b_hh = (const float*)d_in[17];
    const float* lin1_w    = (const float*)d_in[18];
    const float* lin1_b    = (const float*)d_in[19];
    const float* lin2_w    = (const float*)d_in[20];
    const float* lin2_b    = (const float*)d_in[21];
    const int*   edge_index= (const int*)d_in[22];
    const int*   batch     = (const int*)d_in[23];
    float* yout = (float*)d_out;

    char* p = (char*)d_ws;
    auto alloc = [&](size_t bytes) { char* r = p; p += (bytes + 255) & ~(size_t)255; return r; };

    // ---- zero region (one memset) ----
    int*   cursor = (int*)  alloc(NN * sizeof(int));
    int*   acnt   = (int*)  alloc(CAP * 32 * sizeof(int));
    int*   gcur   = (int*)  alloc(NBIN * sizeof(int));
    size_t zero_bytes = (size_t)(p - (char*)d_ws);
    // ---- rest ----
    int*   gstart    = (int*)  alloc((NG + 1) * sizeof(int));
    int*   srt_src   = (int*)  alloc((size_t)NN * CAP * sizeof(int));
    float* srt_ea    = (float*)alloc((size_t)NN * CAP * 2 * sizeof(float));
    float* outA      = (float*)alloc(NN * DIM * sizeof(float));
    float* outB      = (float*)alloc(NN * DIM * sizeof(float));
    int*   perm      = (int*)  alloc(NN * sizeof(int));
    unsigned short* w2f = (unsigned short*)alloc(262144 * sizeof(unsigned short));
    float* ebuf      = (float*)alloc(NN * sizeof(float));
    (void)ws_size; (void)n_in; (void)in_sizes; (void)out_size;

    hipMemsetAsync(d_ws, 0, zero_bytes, stream);

    k_setup<<<1067, 256, 0, stream>>>(nn_w2, w2f, x, lin0_w, lin0_b, outA, batch, gstart,
                                      edge_index, edge_attr, cursor, acnt, srt_src, srt_ea);
    k_scatter<<<40, 256, 0, stream>>>(cursor, acnt, gcur, perm);

    const float* cur = outA;
    float* nxt = outB;
    for (int it = 0; it < 3; ++it) {
        k_conv_gru<<<1250, 512, 0, stream>>>(perm, cursor, srt_src, srt_ea,
                                             nn_w1, nn_b1, w2f, nn_b2,
                                             cur,
                                             conv_root, conv_bias,
                                             gru_w_ih, gru_w_hh, gru_b_ih, gru_b_hh,
                                             nxt);
        const float* tmp = nxt; nxt = (float*)cur; cur = tmp;
    }
    const float* outF = cur;

    k_set2set<<<NG, 256, 0, stream>>>(outF, gstart,
                                      lstm_w_ih, lstm_w_hh, lstm_b_ih, lstm_b_hh,
                                      lin1_w, lin1_b, lin2_w, lin2_b, ebuf, yout);
}

// Round 7
// 346.990 us; speedup vs baseline: 1.0748x; 1.0748x over previous
//
#include <hip/hip_runtime.h>
#include <math.h>

#define NN 10000
#define NE 160000
#define NG 64
#define DIM 32
#define CAP 96   // per-node edge slot capacity (max degree ~40 at Binomial(160K,1e-4))
#define NBIN (CAP + 1)

typedef __attribute__((ext_vector_type(8))) short bf16x8;
typedef __attribute__((ext_vector_type(4))) float f32x4;
typedef __attribute__((ext_vector_type(2))) float f32x2;

__device__ __forceinline__ float sigmoidf_(float x) { return 1.f / (1.f + expf(-x)); }

// round-to-nearest-even fp32 -> bf16 bits
__device__ __forceinline__ unsigned short f2bf(float x) {
    unsigned u = __float_as_uint(x);
    u += 0x7FFF + ((u >> 16) & 1);
    return (unsigned short)(u >> 16);
}
__device__ __forceinline__ float bf2f(unsigned short b) {
    return __uint_as_float(((unsigned)b) << 16);
}
__device__ __forceinline__ float rlanef(float v, int i) {
    return __uint_as_float((unsigned)__builtin_amdgcn_readlane((int)__float_as_uint(v), i));
}

// ---------------------------------------------------------------- fused setup + fill
//   b<128:        W2 -> B-fragment bf16 hi/lo planes (float4 reads, 4 elems/thread)
//                 h' = 2*(h&63)+(h>>6) permuted (matches conv's packed cvt stores)
//   b<441:        lin0 + relu (float4)
//   b==441:       gstart binary search
//   b>=442:       direct-slot edge bucketing (625 blocks) + acnt degree counting:
//                 #nodes with deg > d == #edges whose atomicAdd returned d ->
//                 descending-sort bases come free (sub-banked x32 vs contention).
__global__ void k_setup(const float* __restrict__ w2, unsigned short* __restrict__ w2f,
                        const float* __restrict__ x, const float* __restrict__ lw,
                        const float* __restrict__ lb, float* __restrict__ out,
                        const int* __restrict__ batch, int* __restrict__ gstart,
                        const int* __restrict__ ei, const float* __restrict__ ea,
                        int* __restrict__ cursor, int* __restrict__ acnt,
                        int* __restrict__ srt_src, float* __restrict__ srt_ea) {
    int b = blockIdx.x, t = threadIdx.x;
    if (b < 128) {
        int base = (b * 256 + t) * 4;                 // linear w2 index (coalesced float4)
        float4 v4 = *(const float4*)(w2 + base);
        #pragma unroll
        for (int u = 0; u < 4; ++u) {
            int tid = base + u;
            int h = tid >> 10, rem = tid & 1023, i = rem >> 5, n = rem & 31;
            float v = ((const float*)&v4)[u];
            unsigned short hi = f2bf(v);
            unsigned short lo = f2bf(v - bf2f(hi));
            int hp = 2 * (h & 63) + (h >> 6);         // h' permutation
            int s = hp >> 5, hm = hp & 31, q = hm >> 3, j = hm & 7;
            int tile = n >> 4, nn = n & 15, lane = q * 16 + nn;
            int c = (i * 4 + s) * 2 + tile;
            w2f[(c * 2 + 0) * 512 + lane * 8 + j] = hi;
            w2f[(c * 2 + 1) * 512 + lane * 8 + j] = lo;
        }
    } else if (b < 441) {
        int idx4 = (b - 128) * 256 + t;               // float4 index into out
        if (idx4 < NN * DIM / 4) {
            int n = (idx4 * 4) >> 5, d0 = (idx4 * 4) & 31;
            float xv = x[n];
            float4 wv = *(const float4*)(lw + d0);
            float4 bv = *(const float4*)(lb + d0);
            float4 o;
            o.x = fmaxf(xv * wv.x + bv.x, 0.f);
            o.y = fmaxf(xv * wv.y + bv.y, 0.f);
            o.z = fmaxf(xv * wv.z + bv.z, 0.f);
            o.w = fmaxf(xv * wv.w + bv.w, 0.f);
            *(float4*)(out + idx4 * 4) = o;
        }
    } else if (b == 441) {
        if (t <= NG) {
            int g = t, lo = 0, hi = NN;
            while (lo < hi) { int mid = (lo + hi) >> 1; if (batch[mid] < g) lo = mid + 1; else hi = mid; }
            gstart[g] = lo;
        }
    } else {
        int e = (b - 442) * 256 + t;
        if (e < NE) {
            int d = ei[NE + e];
            int p = atomicAdd(&cursor[d], 1);
            int pos = d * CAP + p;
            srt_src[pos] = ei[e];
            *(float2*)(srt_ea + 2 * pos) = *(const float2*)(ea + 2 * e);
            int pc = p < CAP - 1 ? p : CAP - 1;
            atomicAdd(&acnt[pc * 32 + (t & 31)], 1);  // degree-count, sub-banked
        }
    }
}

// ---------------------------------------------------------------- perm scatter
// Two-phase, contention-free: per-block LDS bin counts (256 adds into ~40 LDS
// bins), ONE global atomicAdd per (block,bin) to claim a contiguous range
// (<=40 contenders per bin address), then LDS-offset scatter. Replaces the
// serial single-block k_perm. base[d] = #nodes with deg > d (from acnt).
__global__ __launch_bounds__(256) void k_scatter(const int* __restrict__ cursor,
                                                 const int* __restrict__ acnt,
                                                 int* __restrict__ gcur,
                                                 int* __restrict__ perm) {
    __shared__ int sbase[NBIN];
    __shared__ int lcnt[NBIN];
    __shared__ int lbase[NBIN];
    int t = threadIdx.x;
    if (t < NBIN) {
        int s = 0;
        if (t < CAP) {
            #pragma unroll
            for (int k = 0; k < 32; ++k) s += acnt[t * 32 + k];
        }
        sbase[t] = s;                                  // base[CAP] = 0
        lcnt[t] = 0;
    }
    __syncthreads();
    int n = blockIdx.x * 256 + t;
    int d = -1;
    if (n < NN) {
        d = cursor[n]; d = d > CAP ? CAP : d;
        atomicAdd(&lcnt[d], 1);                        // LDS, low contention
    }
    __syncthreads();
    if (t < NBIN) {
        int c = lcnt[t];
        lbase[t] = c ? sbase[t] + atomicAdd(&gcur[t], c) : 0;
        lcnt[t] = 0;
    }
    __syncthreads();
    if (n < NN) {
        int off = atomicAdd(&lcnt[d], 1);
        perm[lbase[d] + off] = n;
    }
}

// ---------------------------------------------------------------- NNConv + GRU fused
// R2-verified structure (66.5us, absmax 0.0): 8 waves / 8 nodes / 512 thr;
// pk_fma f32x2 edge accumulation; h'-adjacent packed cvt stores; readlane-
// preloaded edge metadata; Sg through LDS. VERBATIM R2 (epilogue wv<8 — the
// R6 wv<16 copy-through from the 16-wave R5 layout was an OOB-read bug).
#define NS 1040
#define PS 8320
__global__ __launch_bounds__(512, 4) void k_conv_gru(
    const int* __restrict__ perm,
    const int* __restrict__ cursor, const int* __restrict__ srt_src,
    const float* __restrict__ srt_ea,
    const float* __restrict__ w1, const float* __restrict__ b1,
    const unsigned short* __restrict__ w2f, const float* __restrict__ b2,
    const float* __restrict__ out_old,
    const float* __restrict__ root, const float* __restrict__ cbias,
    const float* __restrict__ wih, const float* __restrict__ whh,
    const float* __restrict__ bih, const float* __restrict__ bhh,
    float* __restrict__ out_new)
{
    __shared__ __align__(16) unsigned short RB[2 * PS];   // hi plane + lo plane
    __shared__ float sSg[8][DIM];
    __shared__ int sNode[8];
    int t = threadIdx.x;
    int wave = t >> 6, lane = t & 63;
    int n0 = blockIdx.x * 8;
    int n = perm[n0 + wave];
    if (lane == 0) sNode[wave] = n;

    // ---------------- edge phase ----------------
    f32x2 acc2[32];                       // .x: h'=2*lane, .y: h'=2*lane+1
    #pragma unroll
    for (int i = 0; i < 32; ++i) acc2[i] = (f32x2){0.f, 0.f};
    float sacc = 0.f;

    float w1a0 = w1[lane],      w1c0 = w1[128 + lane],  bb0 = b1[lane];
    float w1a1 = w1[64 + lane], w1c1 = w1[192 + lane],  bb1 = b1[64 + lane];

    int deg = cursor[n];
    int rs = n * CAP;
    const float2* eap = (const float2*)srt_ea;

    int msrc = 0; float mex = 0.f, mey = 0.f;
    if (lane < deg) {
        msrc = srt_src[rs + lane];
        float2 a = eap[rs + lane];
        mex = a.x; mey = a.y;
    }

    int dmain = deg < 64 ? deg : 64;
    int i = 0;
    for (; i + 1 < dmain; i += 2) {
        int s0 = __builtin_amdgcn_readlane(msrc, i);
        int s1 = __builtin_amdgcn_readlane(msrc, i + 1);
        float a0x = rlanef(mex, i),     a0y = rlanef(mey, i);
        float a1x = rlanef(mex, i + 1), a1y = rlanef(mey, i + 1);
        const float* o0 = out_old + s0 * DIM;     // uniform -> s_load
        const float* o1 = out_old + s1 * DIM;     // independent chain
        f32x2 r0 = { fmaxf(a0x * w1a0 + a0y * w1c0 + bb0, 0.f),
                     fmaxf(a0x * w1a1 + a0y * w1c1 + bb1, 0.f) };
        f32x2 r1 = { fmaxf(a1x * w1a0 + a1y * w1c0 + bb0, 0.f),
                     fmaxf(a1x * w1a1 + a1y * w1c1 + bb1, 0.f) };
        #pragma unroll
        for (int q = 0; q < 32; ++q)
            acc2[q] += r0 * o0[q];                // v_pk_fma_f32
        #pragma unroll
        for (int q = 0; q < 32; ++q)
            acc2[q] += r1 * o1[q];
        const float* oc = (lane < 32) ? (o0 + lane) : (o1 + lane - 32);
        sacc += *oc;
    }
    if (i < dmain) {                               // tail edge
        int s0 = __builtin_amdgcn_readlane(msrc, i);
        float a0x = rlanef(mex, i), a0y = rlanef(mey, i);
        const float* o0 = out_old + s0 * DIM;
        f32x2 r0 = { fmaxf(a0x * w1a0 + a0y * w1c0 + bb0, 0.f),
                     fmaxf(a0x * w1a1 + a0y * w1c1 + bb1, 0.f) };
        #pragma unroll
        for (int q = 0; q < 32; ++q)
            acc2[q] += r0 * o0[q];
        if (lane < 32) sacc += o0[lane];
    }
    for (int p = rs + 64; p < rs + deg; ++p) {     // rare fallback deg > 64
        int s0 = __builtin_amdgcn_readfirstlane(srt_src[p]);
        float2 a0 = eap[p];
        const float* o0 = out_old + s0 * DIM;
        f32x2 r0 = { fmaxf(a0.x * w1a0 + a0.y * w1c0 + bb0, 0.f),
                     fmaxf(a0.x * w1a1 + a0.y * w1c1 + bb1, 0.f) };
        #pragma unroll
        for (int q = 0; q < 32; ++q)
            acc2[q] += r0 * o0[q];
        if (lane < 32) sacc += o0[lane];
    }
    sacc += __shfl_xor(sacc, 32);                  // combine the two row-halves
    if (lane < DIM) sSg[wave][lane] = sacc;

    // ---------------- MFMA contraction: 4 i-passes of 8 ----------------
    int quad = lane >> 4;
    int mm = lane & 7;                  // A rows 8..15 dup of 0..7 (unread in D)
    unsigned aoff = (unsigned)(mm * NS + wave * 128 + quad * 8);
    f32x4 acc0 = {0.f, 0.f, 0.f, 0.f};
    f32x4 acc1 = {0.f, 0.f, 0.f, 0.f};

    unsigned short* Hw = RB + wave * NS;
    unsigned short* Lw = RB + PS + wave * NS;

    #pragma unroll
    for (int pass = 0; pass < 4; ++pass) {
        if (pass) __syncthreads();                 // prior pass's reads done
        #pragma unroll
        for (int li = 0; li < 8; ++li) {
            f32x2 v = acc2[pass * 8 + li];         // h'=2*lane (.x), 2*lane+1 (.y)
            unsigned short h0 = f2bf(v.x);
            unsigned short l0 = f2bf(v.x - bf2f(h0));
            unsigned short h1 = f2bf(v.y);
            unsigned short l1 = f2bf(v.y - bf2f(h1));
            *(unsigned*)(Hw + li * 128 + 2 * lane) = (unsigned)h0 | ((unsigned)h1 << 16);
            *(unsigned*)(Lw + li * 128 + 2 * lane) = (unsigned)l0 | ((unsigned)l1 << 16);
        }
        __syncthreads();
        int ig = pass * 8 + wave;                  // global i-row this wave covers
        #pragma unroll
        for (int s = 0; s < 4; ++s) {
            bf16x8 ah = *(const bf16x8*)(RB + aoff + s * 32);
            bf16x8 al = *(const bf16x8*)(RB + PS + aoff + s * 32);
            const unsigned short* bp = w2f + (unsigned)((ig * 4 + s) * 2048 + lane * 8);
            bf16x8 bh0 = *(const bf16x8*)(bp);
            bf16x8 bl0 = *(const bf16x8*)(bp + 512);
            bf16x8 bh1 = *(const bf16x8*)(bp + 1024);
            bf16x8 bl1 = *(const bf16x8*)(bp + 1536);
            acc0 = __builtin_amdgcn_mfma_f32_16x16x32_bf16(ah, bh0, acc0, 0, 0, 0);
            acc0 = __builtin_amdgcn_mfma_f32_16x16x32_bf16(ah, bl0, acc0, 0, 0, 0);
            acc0 = __builtin_amdgcn_mfma_f32_16x16x32_bf16(al, bh0, acc0, 0, 0, 0);
            acc1 = __builtin_amdgcn_mfma_f32_16x16x32_bf16(ah, bh1, acc1, 0, 0, 0);
            acc1 = __builtin_amdgcn_mfma_f32_16x16x32_bf16(ah, bl1, acc1, 0, 0, 0);
            acc1 = __builtin_amdgcn_mfma_f32_16x16x32_bf16(al, bh1, acc1, 0, 0, 0);
        }
    }
    __syncthreads();                               // all RB reads complete

    // ---- K-partial reduction through LDS (reuse RB as float area) ----
    float* part = (float*)RB;                      // 16 tiles x 64 lanes x 4 = 16 KB
    #pragma unroll
    for (int r = 0; r < 4; ++r) {
        part[((wave * 2 + 0) * 64 + lane) * 4 + r] = acc0[r];
        part[((wave * 2 + 1) * 64 + lane) * 4 + r] = acc1[r];
    }
    __syncthreads();

    // ---------------- fused GRU epilogue (threads 0..255: 8 nodes x 32 dims) ----------------
    if (t < 256) {
        int nb = t >> 5, d = t & 31;
        int nn_ = sNode[nb];
        int base = t & 32;                          // shfl base within wave
        // C/D layout: row=(lane>>4)*4+reg, col=lane&15 -> gather this (nb,d)
        int tile = d >> 4, col = d & 15;
        int lidx = (nb >> 2) * 16 + col, reg = nb & 3;
        float aggv = 0.f;
        #pragma unroll
        for (int wv = 0; wv < 8; ++wv)
            aggv += part[((wv * 2 + tile) * 64 + lidx) * 4 + reg];

        float bt = 0.f;
        #pragma unroll 8
        for (int i2 = 0; i2 < DIM; ++i2) bt += sSg[nb][i2] * b2[i2 * DIM + d];
        int cdeg = cursor[nn_];
        float degf = (float)(cdeg > 0 ? cdeg : 1);
        aggv = (aggv + bt) / degf;

        float x = out_old[nn_ * DIM + d];           // h_old[d]
        float rootsum = 0.f;
        #pragma unroll 8
        for (int k = 0; k < DIM; ++k)
            rootsum += __shfl(x, base + k) * root[k * DIM + d];
        float m = fmaxf(aggv + rootsum + cbias[d], 0.f);

        float gir = bih[d], giz = bih[DIM + d], gin = bih[2 * DIM + d];
        float ghr = bhh[d], ghz = bhh[DIM + d], ghn = bhh[2 * DIM + d];
        #pragma unroll 4
        for (int k = 0; k < DIM; ++k) {
            float mk = __shfl(m, base + k);
            float hk = __shfl(x, base + k);
            gir += mk * wih[k * 96 + d];
            giz += mk * wih[k * 96 + DIM + d];
            gin += mk * wih[k * 96 + 2 * DIM + d];
            ghr += hk * whh[k * 96 + d];
            ghz += hk * whh[k * 96 + DIM + d];
            ghn += hk * whh[k * 96 + 2 * DIM + d];
        }
        float rg = sigmoidf_(gir + ghr);
        float zg = sigmoidf_(giz + ghz);
        float ng = tanhf(gin + rg * ghn);
        out_new[nn_ * DIM + d] = (1.f - zg) * ng + zg * x;
    }
}

// ---------------------------------------------------------------- Set2Set + head (R2-verified)
__global__ __launch_bounds__(256) void k_set2set(
    const float* __restrict__ out, const int* __restrict__ gstart,
    const float* __restrict__ wih, const float* __restrict__ whh,
    const float* __restrict__ bih, const float* __restrict__ bhh,
    const float* __restrict__ l1w, const float* __restrict__ l1b,
    const float* __restrict__ l2w, const float* __restrict__ l2b,
    float* __restrict__ ebuf, float* __restrict__ y)
{
    __shared__ float swih[64 * 128];   // 32 KB
    __shared__ float swhh[32 * 128];   // 16 KB
    __shared__ float sq[2 * DIM];
    __shared__ float shh[DIM], scc[DIM];
    __shared__ float sgates[4 * DIM];
    __shared__ float sacc[8][DIM];
    __shared__ float sredA[4], sredB[4];

    int g = blockIdx.x, t = threadIdx.x;
    {
        const float4* wv = (const float4*)wih;   float4* sv = (float4*)swih;
        for (int i = t; i < 2048; i += 256) sv[i] = wv[i];
        const float4* wv2 = (const float4*)whh;  float4* sv2 = (float4*)swhh;
        for (int i = t; i < 1024; i += 256) sv2[i] = wv2[i];
    }
    if (t < 2 * DIM) sq[t] = 0.f;
    if (t < DIM) { shh[t] = 0.f; scc[t] = 0.f; }
    int ns = gstart[g], ne = gstart[g + 1];
    __syncthreads();

    for (int step = 0; step < 3; ++step) {
        if (t < 128) {
            float acc = bih[t] + bhh[t];
            #pragma unroll 8
            for (int k = 0; k < 2 * DIM; ++k) acc += sq[k] * swih[k * 128 + t];
            #pragma unroll 8
            for (int k = 0; k < DIM; ++k)     acc += shh[k] * swhh[k * 128 + t];
            sgates[t] = acc;
        }
        __syncthreads();
        if (t < DIM) {
            float ig = sigmoidf_(sgates[t]);
            float fg = sigmoidf_(sgates[DIM + t]);
            float gg = tanhf(sgates[2 * DIM + t]);
            float og = sigmoidf_(sgates[3 * DIM + t]);
            float c_new = fg * scc[t] + ig * gg;
            float h_new = og * tanhf(c_new);
            scc[t] = c_new;
            shh[t] = h_new;
            sq[t] = h_new;
        }
        __syncthreads();

        float lmax = -3.0e38f;
        for (int n = ns + t; n < ne; n += 256) {
            const float4* orow = (const float4*)(out + n * DIM);
            float e = 0.f;
            #pragma unroll
            for (int q = 0; q < 8; ++q) {
                float4 o4 = orow[q];
                e += o4.x * shh[4 * q] + o4.y * shh[4 * q + 1]
                   + o4.z * shh[4 * q + 2] + o4.w * shh[4 * q + 3];
            }
            ebuf[n] = e;
            lmax = fmaxf(lmax, e);
        }
        #pragma unroll
        for (int s = 1; s < 64; s <<= 1) lmax = fmaxf(lmax, __shfl_xor(lmax, s));
        if ((t & 63) == 0) sredA[t >> 6] = lmax;
        __syncthreads();
        float M = fmaxf(fmaxf(sredA[0], sredA[1]), fmaxf(sredA[2], sredA[3]));

        float lsum = 0.f;
        for (int n = ns + t; n < ne; n += 256) {
            float v = expf(ebuf[n] - M);
            ebuf[n] = v;
            lsum += v;
        }
        #pragma unroll
        for (int s = 1; s < 64; s <<= 1) lsum += __shfl_xor(lsum, s);
        if ((t & 63) == 0) sredB[t >> 6] = lsum;
        __syncthreads();
        float S = sredB[0] + sredB[1] + sredB[2] + sredB[3];
        float inv = (S > 0.f) ? 1.f / S : 0.f;

        int stp = t >> 5, d = t & 31;
        float racc = 0.f;
        for (int n = ns + stp; n < ne; n += 8)
            racc += ebuf[n] * out[n * DIM + d];
        sacc[stp][d] = racc;
        __syncthreads();
        if (t < DIM) {
            float r = 0.f;
            #pragma unroll
            for (int s = 0; s < 8; ++s) r += sacc[s][t];
            sq[DIM + t] = r * inv;
        }
        __syncthreads();
    }

    if (t < DIM) {
        float h = l1b[t];
        #pragma unroll 8
        for (int k = 0; k < 2 * DIM; ++k) h += sq[k] * l1w[k * DIM + t];
        float v = fmaxf(h, 0.f) * l2w[t];
        #pragma unroll
        for (int s = 1; s < 32; s <<= 1) v += __shfl_xor(v, s);
        if (t == 0) y[g] = v + l2b[0];
    }
}

// ---------------------------------------------------------------- launch
extern "C" void kernel_launch(void* const* d_in, const int* in_sizes, int n_in,
                              void* d_out, int out_size, void* d_ws, size_t ws_size,
                              hipStream_t stream) {
    const float* x         = (const float*)d_in[0];
    const float* edge_attr = (const float*)d_in[1];
    const float* lin0_w    = (const float*)d_in[2];
    const float* lin0_b    = (const float*)d_in[3];
    const float* nn_w1     = (const float*)d_in[4];
    const float* nn_b1     = (const float*)d_in[5];
    const float* nn_w2     = (const float*)d_in[6];
    const float* nn_b2     = (const float*)d_in[7];
    const float* conv_root = (const float*)d_in[8];
    const float* conv_bias = (const float*)d_in[9];
    const float* gru_w_ih  = (const float*)d_in[10];
    const float* gru_w_hh  = (const float*)d_in[11];
    const float* gru_b_ih  = (const float*)d_in[12];
    const float* gru_b_hh  = (const float*)d_in[13];
    const float* lstm_w_ih = (const float*)d_in[14];
    const float* lstm_w_hh = (const float*)d_in[15];
    const float* lstm_b_ih = (const float*)d_in[16];
    const float* lstm_b_hh = (const float*)d_in[17];
    const float* lin1_w    = (const float*)d_in[18];
    const float* lin1_b    = (const float*)d_in[19];
    const float* lin2_w    = (const float*)d_in[20];
    const float* lin2_b    = (const float*)d_in[21];
    const int*   edge_index= (const int*)d_in[22];
    const int*   batch     = (const int*)d_in[23];
    float* yout = (float*)d_out;

    char* p = (char*)d_ws;
    auto alloc = [&](size_t bytes) { char* r = p; p += (bytes + 255) & ~(size_t)255; return r; };

    // ---- zero region (one memset) ----
    int*   cursor = (int*)  alloc(NN * sizeof(int));
    int*   acnt   = (int*)  alloc(CAP * 32 * sizeof(int));
    int*   gcur   = (int*)  alloc(NBIN * sizeof(int));
    size_t zero_bytes = (size_t)(p - (char*)d_ws);
    // ---- rest ----
    int*   gstart    = (int*)  alloc((NG + 1) * sizeof(int));
    int*   srt_src   = (int*)  alloc((size_t)NN * CAP * sizeof(int));
    float* srt_ea    = (float*)alloc((size_t)NN * CAP * 2 * sizeof(float));
    float* outA      = (float*)alloc(NN * DIM * sizeof(float));
    float* outB      = (float*)alloc(NN * DIM * sizeof(float));
    int*   perm      = (int*)  alloc(NN * sizeof(int));
    unsigned short* w2f = (unsigned short*)alloc(262144 * sizeof(unsigned short));
    float* ebuf      = (float*)alloc(NN * sizeof(float));
    (void)ws_size; (void)n_in; (void)in_sizes; (void)out_size;

    hipMemsetAsync(d_ws, 0, zero_bytes, stream);

    k_setup<<<1067, 256, 0, stream>>>(nn_w2, w2f, x, lin0_w, lin0_b, outA, batch, gstart,
                                      edge_index, edge_attr, cursor, acnt, srt_src, srt_ea);
    k_scatter<<<40, 256, 0, stream>>>(cursor, acnt, gcur, perm);

    const float* cur = outA;
    float* nxt = outB;
    for (int it = 0; it < 3; ++it) {
        k_conv_gru<<<1250, 512, 0, stream>>>(perm, cursor, srt_src, srt_ea,
                                             nn_w1, nn_b1, w2f, nn_b2,
                                             cur,
                                             conv_root, conv_bias,
                                             gru_w_ih, gru_w_hh, gru_b_ih, gru_b_hh,
                                             nxt);
        const float* tmp = nxt; nxt = (float*)cur; cur = tmp;
    }
    const float* outF = cur;

    k_set2set<<<NG, 256, 0, stream>>>(outF, gstart,
                                      lstm_w_ih, lstm_w_hh, lstm_b_ih, lstm_b_hh,
                                      lin1_w, lin1_b, lin2_w, lin2_b, ebuf, yout);
}

// Round 8
// 343.604 us; speedup vs baseline: 1.0854x; 1.0099x over previous
//
#include <hip/hip_runtime.h>
#include <math.h>

#define NN 10000
#define NE 160000
#define NG 64
#define DIM 32
#define CAP 96   // per-node edge slot capacity (max degree ~40 at Binomial(160K,1e-4))
#define NBIN (CAP + 1)

typedef __attribute__((ext_vector_type(8))) short bf16x8;
typedef __attribute__((ext_vector_type(4))) float f32x4;
typedef __attribute__((ext_vector_type(2))) float f32x2;

__device__ __forceinline__ float sigmoidf_(float x) { return 1.f / (1.f + expf(-x)); }

// round-to-nearest-even fp32 -> bf16 bits
__device__ __forceinline__ unsigned short f2bf(float x) {
    unsigned u = __float_as_uint(x);
    u += 0x7FFF + ((u >> 16) & 1);
    return (unsigned short)(u >> 16);
}
__device__ __forceinline__ float bf2f(unsigned short b) {
    return __uint_as_float(((unsigned)b) << 16);
}
__device__ __forceinline__ float rlanef(float v, int i) {
    return __uint_as_float((unsigned)__builtin_amdgcn_readlane((int)__float_as_uint(v), i));
}

// ---------------------------------------------------------------- fused setup + fill
// R1/R2-verified (rest = 111-119 us twice; the R6/R7 float4+acnt variant cost +25).
//   b<512:        W2 -> B-fragment bf16 hi/lo planes, h' = 2*(h&63)+(h>>6) permuted
//   b<1762:       lin0 + relu
//   b==1762:      gstart binary search
//   b>=1763:      direct-slot edge bucketing (625 blocks)
__global__ void k_setup(const float* __restrict__ w2, unsigned short* __restrict__ w2f,
                        const float* __restrict__ x, const float* __restrict__ lw,
                        const float* __restrict__ lb, float* __restrict__ out,
                        const int* __restrict__ batch, int* __restrict__ gstart,
                        const int* __restrict__ ei, const float* __restrict__ ea,
                        int* __restrict__ cursor,
                        int* __restrict__ srt_src, float* __restrict__ srt_ea) {
    int b = blockIdx.x, t = threadIdx.x;
    if (b < 512) {
        int tid = b * 256 + t;                        // linear w2 index (coalesced)
        int h = tid >> 10, rem = tid & 1023, i = rem >> 5, n = rem & 31;
        float v = w2[tid];
        unsigned short hi = f2bf(v);
        unsigned short lo = f2bf(v - bf2f(hi));
        int hp = 2 * (h & 63) + (h >> 6);             // h' permutation
        int s = hp >> 5, hm = hp & 31, q = hm >> 3, j = hm & 7;
        int tile = n >> 4, nn = n & 15, lane = q * 16 + nn;
        int c = (i * 4 + s) * 2 + tile;
        w2f[(c * 2 + 0) * 512 + lane * 8 + j] = hi;
        w2f[(c * 2 + 1) * 512 + lane * 8 + j] = lo;
    } else if (b < 1762) {
        int idx = (b - 512) * 256 + t;               // < NN*DIM
        int n = idx >> 5, d = idx & 31;
        out[idx] = fmaxf(x[n] * lw[d] + lb[d], 0.f);
    } else if (b == 1762) {
        if (t <= NG) {
            int g = t, lo = 0, hi = NN;
            while (lo < hi) { int mid = (lo + hi) >> 1; if (batch[mid] < g) lo = mid + 1; else hi = mid; }
            gstart[g] = lo;
        }
    } else {
        int e = (b - 1763) * 256 + t;
        if (e < NE) {
            int d = ei[NE + e];
            int p = atomicAdd(&cursor[d], 1);
            int pos = d * CAP + p;
            srt_src[pos] = ei[e];
            srt_ea[2 * pos]     = ea[2 * e];
            srt_ea[2 * pos + 1] = ea[2 * e + 1];
        }
    }
}

// ---------------------------------------------------------------- degree-sorted node order
// R1-verified counting sort, DESCENDING. Single block; 16 sub-histograms.
__global__ __launch_bounds__(1024) void k_perm(const int* __restrict__ cursor,
                                               int* __restrict__ perm) {
    __shared__ int hist[NBIN * 16];
    __shared__ int binsum[NBIN];
    __shared__ int base[NBIN];
    int t = threadIdx.x;
    for (int i = t; i < NBIN * 16; i += 1024) hist[i] = 0;
    __syncthreads();
    int sub = t & 15;
    for (int n = t; n < NN; n += 1024) {
        int d = cursor[n]; d = d > CAP ? CAP : d;
        atomicAdd(&hist[d * 16 + sub], 1);
    }
    __syncthreads();
    if (t < NBIN) {
        int s = 0;
        #pragma unroll
        for (int k = 0; k < 16; ++k) s += hist[t * 16 + k];
        binsum[t] = s;
    }
    __syncthreads();
    if (t == 0) {
        int acc = 0;
        for (int d = CAP; d >= 0; --d) { base[d] = acc; acc += binsum[d]; }  // descending
    }
    __syncthreads();
    if (t < NBIN) {                      // exclusive prefix over the 16 sub-counters
        int acc = base[t];
        #pragma unroll
        for (int k = 0; k < 16; ++k) {
            int c = hist[t * 16 + k];
            hist[t * 16 + k] = acc;
            acc += c;
        }
    }
    __syncthreads();
    for (int n = t; n < NN; n += 1024) {
        int d = cursor[n]; d = d > CAP ? CAP : d;
        int pos = atomicAdd(&hist[d * 16 + sub], 1);
        perm[pos] = n;
    }
}

// ---------------------------------------------------------------- NNConv + GRU fused
// R8 edge phase: LDS row staging + rolled broadcast consume.
//  - gather <=32 rows per wave in 4 independent per-lane float4 loads (src ids
//    via ds_bpermute from preloaded metadata) -> ds_write_b128 into a 4 KB
//    per-wave slice of RB (idle until contraction; new barrier protects reuse).
//  - consume: rolled per-edge loop, 8 uniform ds_read_b128 broadcasts + 32
//    pk_fma. No dependent L2 waits on the critical path; row traffic unchanged.
//  - acc2 op order bit-identical to R2; sacc grouping differs (ulp-level).
// Contraction/epilogue: R2-verified verbatim.
#define NS 1040
#define PS 8320
__global__ __launch_bounds__(512, 4) void k_conv_gru(
    const int* __restrict__ perm,
    const int* __restrict__ cursor, const int* __restrict__ srt_src,
    const float* __restrict__ srt_ea,
    const float* __restrict__ w1, const float* __restrict__ b1,
    const unsigned short* __restrict__ w2f, const float* __restrict__ b2,
    const float* __restrict__ out_old,
    const float* __restrict__ root, const float* __restrict__ cbias,
    const float* __restrict__ wih, const float* __restrict__ whh,
    const float* __restrict__ bih, const float* __restrict__ bhh,
    float* __restrict__ out_new)
{
    __shared__ __align__(16) unsigned short RB[2 * PS];   // hi plane + lo plane (33.3 KB)
    __shared__ float sSg[8][DIM];
    __shared__ int sNode[8];
    int t = threadIdx.x;
    int wave = t >> 6, lane = t & 63;
    int n0 = blockIdx.x * 8;
    int n = perm[n0 + wave];
    if (lane == 0) sNode[wave] = n;

    // ---------------- edge phase ----------------
    f32x2 acc2[32];                       // .x: h'=2*lane, .y: h'=2*lane+1
    #pragma unroll
    for (int i = 0; i < 32; ++i) acc2[i] = (f32x2){0.f, 0.f};
    float sacc = 0.f;

    float w1a0 = w1[lane],      w1c0 = w1[128 + lane],  bb0 = b1[lane];
    float w1a1 = w1[64 + lane], w1c1 = w1[192 + lane],  bb1 = b1[64 + lane];

    int deg = cursor[n];
    int rs = n * CAP;
    const float2* eap = (const float2*)srt_ea;

    // lane-parallel preload of edge metadata (lane -> edge; covers deg<=64)
    int msrc = 0; float mex = 0.f, mey = 0.f;
    if (lane < deg) {
        msrc = srt_src[rs + lane];
        float2 a = eap[rs + lane];
        mex = a.x; mey = a.y;
    }

    float* stage = (float*)RB + wave * 1024;   // 4 KB per-wave staging (RB reused)
    int dmain = deg < 64 ? deg : 64;

    for (int c = 0; c < dmain; c += 32) {
        int cn = dmain - c; cn = cn < 32 ? cn : 32;
        int nk = (cn + 7) >> 3;
        // gather: load k covers rows c+8k .. c+8k+7; lane l -> row l>>3, dims (l&7)*4
        for (int k = 0; k < nk; ++k) {
            int eidx = c + k * 8 + (lane >> 3);
            int ecl = eidx < deg ? eidx : deg - 1;            // clamp (valid mem)
            int rid = __builtin_amdgcn_ds_bpermute(ecl << 2, msrc);
            float4 v = *(const float4*)(out_old + rid * DIM + (lane & 7) * 4);
            *(float4*)(stage + (k * 8 + (lane >> 3)) * DIM + (lane & 7) * 4) = v;
        }
        // consume: rolled edge loop, uniform LDS broadcasts
        for (int e = 0; e < cn; ++e) {
            int eg = c + e;
            float ax = rlanef(mex, eg);
            float ay = rlanef(mey, eg);
            f32x2 r0 = { fmaxf(ax * w1a0 + ay * w1c0 + bb0, 0.f),
                         fmaxf(ax * w1a1 + ay * w1c1 + bb1, 0.f) };
            const float* sx = stage + e * DIM;
            #pragma unroll
            for (int q = 0; q < 32; ++q)
                acc2[q] += r0 * sx[q];                         // v_pk_fma_f32
        }
        // Sg partials from staged rows (lanes<32: rows 0-15, lanes>=32: rows 16-31)
        {
            int half16 = (lane >> 5) * 16;
            int dd = lane & 31;
            #pragma unroll
            for (int jj = 0; jj < 16; ++jj) {
                int row = half16 + jj;
                float v = stage[row * DIM + dd];
                if (c + row < dmain) sacc += v;
            }
        }
    }
    for (int p = rs + 64; p < rs + deg; ++p) {     // rare fallback deg > 64
        int s0 = __builtin_amdgcn_readfirstlane(srt_src[p]);
        float2 a0 = eap[p];
        const float* o0 = out_old + s0 * DIM;
        f32x2 r0 = { fmaxf(a0.x * w1a0 + a0.y * w1c0 + bb0, 0.f),
                     fmaxf(a0.x * w1a1 + a0.y * w1c1 + bb1, 0.f) };
        #pragma unroll
        for (int q = 0; q < 32; ++q)
            acc2[q] += r0 * o0[q];
        if (lane < 32) sacc += o0[lane];
    }
    sacc += __shfl_xor(sacc, 32);                  // combine the two row-halves
    if (lane < DIM) sSg[wave][lane] = sacc;
    __syncthreads();                               // staging reads done before RB reuse

    // ---------------- MFMA contraction: 4 i-passes of 8 ----------------
    int quad = lane >> 4;
    int mm = lane & 7;                  // A rows 8..15 dup of 0..7 (unread in D)
    unsigned aoff = (unsigned)(mm * NS + wave * 128 + quad * 8);
    f32x4 acc0 = {0.f, 0.f, 0.f, 0.f};
    f32x4 acc1 = {0.f, 0.f, 0.f, 0.f};

    unsigned short* Hw = RB + wave * NS;
    unsigned short* Lw = RB + PS + wave * NS;

    #pragma unroll
    for (int pass = 0; pass < 4; ++pass) {
        if (pass) __syncthreads();                 // prior pass's reads done
        #pragma unroll
        for (int li = 0; li < 8; ++li) {
            f32x2 v = acc2[pass * 8 + li];         // h'=2*lane (.x), 2*lane+1 (.y)
            unsigned short h0 = f2bf(v.x);
            unsigned short l0 = f2bf(v.x - bf2f(h0));
            unsigned short h1 = f2bf(v.y);
            unsigned short l1 = f2bf(v.y - bf2f(h1));
            *(unsigned*)(Hw + li * 128 + 2 * lane) = (unsigned)h0 | ((unsigned)h1 << 16);
            *(unsigned*)(Lw + li * 128 + 2 * lane) = (unsigned)l0 | ((unsigned)l1 << 16);
        }
        __syncthreads();
        int ig = pass * 8 + wave;                  // global i-row this wave covers
        #pragma unroll
        for (int s = 0; s < 4; ++s) {
            bf16x8 ah = *(const bf16x8*)(RB + aoff + s * 32);
            bf16x8 al = *(const bf16x8*)(RB + PS + aoff + s * 32);
            const unsigned short* bp = w2f + (unsigned)((ig * 4 + s) * 2048 + lane * 8);
            bf16x8 bh0 = *(const bf16x8*)(bp);
            bf16x8 bl0 = *(const bf16x8*)(bp + 512);
            bf16x8 bh1 = *(const bf16x8*)(bp + 1024);
            bf16x8 bl1 = *(const bf16x8*)(bp + 1536);
            acc0 = __builtin_amdgcn_mfma_f32_16x16x32_bf16(ah, bh0, acc0, 0, 0, 0);
            acc0 = __builtin_amdgcn_mfma_f32_16x16x32_bf16(ah, bl0, acc0, 0, 0, 0);
            acc0 = __builtin_amdgcn_mfma_f32_16x16x32_bf16(al, bh0, acc0, 0, 0, 0);
            acc1 = __builtin_amdgcn_mfma_f32_16x16x32_bf16(ah, bh1, acc1, 0, 0, 0);
            acc1 = __builtin_amdgcn_mfma_f32_16x16x32_bf16(ah, bl1, acc1, 0, 0, 0);
            acc1 = __builtin_amdgcn_mfma_f32_16x16x32_bf16(al, bh1, acc1, 0, 0, 0);
        }
    }
    __syncthreads();                               // all RB reads complete

    // ---- K-partial reduction through LDS (reuse RB as float area) ----
    float* part = (float*)RB;                      // 16 tiles x 64 lanes x 4 = 16 KB
    #pragma unroll
    for (int r = 0; r < 4; ++r) {
        part[((wave * 2 + 0) * 64 + lane) * 4 + r] = acc0[r];
        part[((wave * 2 + 1) * 64 + lane) * 4 + r] = acc1[r];
    }
    __syncthreads();

    // ---------------- fused GRU epilogue (threads 0..255: 8 nodes x 32 dims) ----------------
    if (t < 256) {
        int nb = t >> 5, d = t & 31;
        int nn_ = sNode[nb];
        int base = t & 32;                          // shfl base within wave
        // C/D layout: row=(lane>>4)*4+reg, col=lane&15 -> gather this (nb,d)
        int tile = d >> 4, col = d & 15;
        int lidx = (nb >> 2) * 16 + col, reg = nb & 3;
        float aggv = 0.f;
        #pragma unroll
        for (int wv = 0; wv < 8; ++wv)
            aggv += part[((wv * 2 + tile) * 64 + lidx) * 4 + reg];

        float bt = 0.f;
        #pragma unroll 8
        for (int i2 = 0; i2 < DIM; ++i2) bt += sSg[nb][i2] * b2[i2 * DIM + d];
        int cdeg = cursor[nn_];
        float degf = (float)(cdeg > 0 ? cdeg : 1);
        aggv = (aggv + bt) / degf;

        float x = out_old[nn_ * DIM + d];           // h_old[d]
        float rootsum = 0.f;
        #pragma unroll 8
        for (int k = 0; k < DIM; ++k)
            rootsum += __shfl(x, base + k) * root[k * DIM + d];
        float m = fmaxf(aggv + rootsum + cbias[d], 0.f);

        float gir = bih[d], giz = bih[DIM + d], gin = bih[2 * DIM + d];
        float ghr = bhh[d], ghz = bhh[DIM + d], ghn = bhh[2 * DIM + d];
        #pragma unroll 4
        for (int k = 0; k < DIM; ++k) {
            float mk = __shfl(m, base + k);
            float hk = __shfl(x, base + k);
            gir += mk * wih[k * 96 + d];
            giz += mk * wih[k * 96 + DIM + d];
            gin += mk * wih[k * 96 + 2 * DIM + d];
            ghr += hk * whh[k * 96 + d];
            ghz += hk * whh[k * 96 + DIM + d];
            ghn += hk * whh[k * 96 + 2 * DIM + d];
        }
        float rg = sigmoidf_(gir + ghr);
        float zg = sigmoidf_(giz + ghz);
        float ng = tanhf(gin + rg * ghn);
        out_new[nn_ * DIM + d] = (1.f - zg) * ng + zg * x;
    }
}

// ---------------------------------------------------------------- Set2Set + head (R2-verified)
__global__ __launch_bounds__(256) void k_set2set(
    const float* __restrict__ out, const int* __restrict__ gstart,
    const float* __restrict__ wih, const float* __restrict__ whh,
    const float* __restrict__ bih, const float* __restrict__ bhh,
    const float* __restrict__ l1w, const float* __restrict__ l1b,
    const float* __restrict__ l2w, const float* __restrict__ l2b,
    float* __restrict__ ebuf, float* __restrict__ y)
{
    __shared__ float swih[64 * 128];   // 32 KB
    __shared__ float swhh[32 * 128];   // 16 KB
    __shared__ float sq[2 * DIM];
    __shared__ float shh[DIM], scc[DIM];
    __shared__ float sgates[4 * DIM];
    __shared__ float sacc[8][DIM];
    __shared__ float sredA[4], sredB[4];

    int g = blockIdx.x, t = threadIdx.x;
    {
        const float4* wv = (const float4*)wih;   float4* sv = (float4*)swih;
        for (int i = t; i < 2048; i += 256) sv[i] = wv[i];
        const float4* wv2 = (const float4*)whh;  float4* sv2 = (float4*)swhh;
        for (int i = t; i < 1024; i += 256) sv2[i] = wv2[i];
    }
    if (t < 2 * DIM) sq[t] = 0.f;
    if (t < DIM) { shh[t] = 0.f; scc[t] = 0.f; }
    int ns = gstart[g], ne = gstart[g + 1];
    __syncthreads();

    for (int step = 0; step < 3; ++step) {
        if (t < 128) {
            float acc = bih[t] + bhh[t];
            #pragma unroll 8
            for (int k = 0; k < 2 * DIM; ++k) acc += sq[k] * swih[k * 128 + t];
            #pragma unroll 8
            for (int k = 0; k < DIM; ++k)     acc += shh[k] * swhh[k * 128 + t];
            sgates[t] = acc;
        }
        __syncthreads();
        if (t < DIM) {
            float ig = sigmoidf_(sgates[t]);
            float fg = sigmoidf_(sgates[DIM + t]);
            float gg = tanhf(sgates[2 * DIM + t]);
            float og = sigmoidf_(sgates[3 * DIM + t]);
            float c_new = fg * scc[t] + ig * gg;
            float h_new = og * tanhf(c_new);
            scc[t] = c_new;
            shh[t] = h_new;
            sq[t] = h_new;
        }
        __syncthreads();

        float lmax = -3.0e38f;
        for (int n = ns + t; n < ne; n += 256) {
            const float4* orow = (const float4*)(out + n * DIM);
            float e = 0.f;
            #pragma unroll
            for (int q = 0; q < 8; ++q) {
                float4 o4 = orow[q];
                e += o4.x * shh[4 * q] + o4.y * shh[4 * q + 1]
                   + o4.z * shh[4 * q + 2] + o4.w * shh[4 * q + 3];
            }
            ebuf[n] = e;
            lmax = fmaxf(lmax, e);
        }
        #pragma unroll
        for (int s = 1; s < 64; s <<= 1) lmax = fmaxf(lmax, __shfl_xor(lmax, s));
        if ((t & 63) == 0) sredA[t >> 6] = lmax;
        __syncthreads();
        float M = fmaxf(fmaxf(sredA[0], sredA[1]), fmaxf(sredA[2], sredA[3]));

        float lsum = 0.f;
        for (int n = ns + t; n < ne; n += 256) {
            float v = expf(ebuf[n] - M);
            ebuf[n] = v;
            lsum += v;
        }
        #pragma unroll
        for (int s = 1; s < 64; s <<= 1) lsum += __shfl_xor(lsum, s);
        if ((t & 63) == 0) sredB[t >> 6] = lsum;
        __syncthreads();
        float S = sredB[0] + sredB[1] + sredB[2] + sredB[3];
        float inv = (S > 0.f) ? 1.f / S : 0.f;

        int stp = t >> 5, d = t & 31;
        float racc = 0.f;
        for (int n = ns + stp; n < ne; n += 8)
            racc += ebuf[n] * out[n * DIM + d];
        sacc[stp][d] = racc;
        __syncthreads();
        if (t < DIM) {
            float r = 0.f;
            #pragma unroll
            for (int s = 0; s < 8; ++s) r += sacc[s][t];
            sq[DIM + t] = r * inv;
        }
        __syncthreads();
    }

    if (t < DIM) {
        float h = l1b[t];
        #pragma unroll 8
        for (int k = 0; k < 2 * DIM; ++k) h += sq[k] * l1w[k * DIM + t];
        float v = fmaxf(h, 0.f) * l2w[t];
        #pragma unroll
        for (int s = 1; s < 32; s <<= 1) v += __shfl_xor(v, s);
        if (t == 0) y[g] = v + l2b[0];
    }
}

// ---------------------------------------------------------------- launch
extern "C" void kernel_launch(void* const* d_in, const int* in_sizes, int n_in,
                              void* d_out, int out_size, void* d_ws, size_t ws_size,
                              hipStream_t stream) {
    const float* x         = (const float*)d_in[0];
    const float* edge_attr = (const float*)d_in[1];
    const float* lin0_w    = (const float*)d_in[2];
    const float* lin0_b    = (const float*)d_in[3];
    const float* nn_w1     = (const float*)d_in[4];
    const float* nn_b1     = (const float*)d_in[5];
    const float* nn_w2     = (const float*)d_in[6];
    const float* nn_b2     = (const float*)d_in[7];
    const float* conv_root = (const float*)d_in[8];
    const float* conv_bias = (const float*)d_in[9];
    const float* gru_w_ih  = (const float*)d_in[10];
    const float* gru_w_hh  = (const float*)d_in[11];
    const float* gru_b_ih  = (const float*)d_in[12];
    const float* gru_b_hh  = (const float*)d_in[13];
    const float* lstm_w_ih = (const float*)d_in[14];
    const float* lstm_w_hh = (const float*)d_in[15];
    const float* lstm_b_ih = (const float*)d_in[16];
    const float* lstm_b_hh = (const float*)d_in[17];
    const float* lin1_w    = (const float*)d_in[18];
    const float* lin1_b    = (const float*)d_in[19];
    const float* lin2_w    = (const float*)d_in[20];
    const float* lin2_b    = (const float*)d_in[21];
    const int*   edge_index= (const int*)d_in[22];
    const int*   batch     = (const int*)d_in[23];
    float* yout = (float*)d_out;

    char* p = (char*)d_ws;
    auto alloc = [&](size_t bytes) { char* r = p; p += (bytes + 255) & ~(size_t)255; return r; };

    // ---- zero region (one memset) ----
    int*   cursor = (int*)  alloc(NN * sizeof(int));
    size_t zero_bytes = (size_t)(p - (char*)d_ws);
    // ---- rest ----
    int*   gstart    = (int*)  alloc((NG + 1) * sizeof(int));
    int*   srt_src   = (int*)  alloc((size_t)NN * CAP * sizeof(int));
    float* srt_ea    = (float*)alloc((size_t)NN * CAP * 2 * sizeof(float));
    float* outA      = (float*)alloc(NN * DIM * sizeof(float));
    float* outB      = (float*)alloc(NN * DIM * sizeof(float));
    int*   perm      = (int*)  alloc(NN * sizeof(int));
    unsigned short* w2f = (unsigned short*)alloc(262144 * sizeof(unsigned short));
    float* ebuf      = (float*)alloc(NN * sizeof(float));
    (void)ws_size; (void)n_in; (void)in_sizes; (void)out_size;

    hipMemsetAsync(d_ws, 0, zero_bytes, stream);

    k_setup<<<2388, 256, 0, stream>>>(nn_w2, w2f, x, lin0_w, lin0_b, outA, batch, gstart,
                                      edge_index, edge_attr, cursor, srt_src, srt_ea);
    k_perm<<<1, 1024, 0, stream>>>(cursor, perm);

    const float* cur = outA;
    float* nxt = outB;
    for (int it = 0; it < 3; ++it) {
        k_conv_gru<<<1250, 512, 0, stream>>>(perm, cursor, srt_src, srt_ea,
                                             nn_w1, nn_b1, w2f, nn_b2,
                                             cur,
                                             conv_root, conv_bias,
                                             gru_w_ih, gru_w_hh, gru_b_ih, gru_b_hh,
                                             nxt);
        const float* tmp = nxt; nxt = (float*)cur; cur = tmp;
    }
    const float* outF = cur;

    k_set2set<<<NG, 256, 0, stream>>>(outF, gstart,
                                      lstm_w_ih, lstm_w_hh, lstm_b_ih, lstm_b_hh,
                                      lin1_w, lin1_b, lin2_w, lin2_b, ebuf, yout);
}

// Round 9
// 312.016 us; speedup vs baseline: 1.1953x; 1.1012x over previous
//
#include <hip/hip_runtime.h>
#include <math.h>

#define NN 10000
#define NE 160000
#define NG 64
#define DIM 32
#define CAP 96   // per-node edge slot capacity (max degree ~40 at Binomial(160K,1e-4))
#define NBIN (CAP + 1)

typedef __attribute__((ext_vector_type(8))) short bf16x8;
typedef __attribute__((ext_vector_type(4))) float f32x4;
typedef __attribute__((ext_vector_type(2))) float f32x2;

__device__ __forceinline__ float sigmoidf_(float x) { return 1.f / (1.f + expf(-x)); }

// round-to-nearest-even fp32 -> bf16 bits
__device__ __forceinline__ unsigned short f2bf(float x) {
    unsigned u = __float_as_uint(x);
    u += 0x7FFF + ((u >> 16) & 1);
    return (unsigned short)(u >> 16);
}
__device__ __forceinline__ float bf2f(unsigned short b) {
    return __uint_as_float(((unsigned)b) << 16);
}
__device__ __forceinline__ float rlanef(float v, int i) {
    return __uint_as_float((unsigned)__builtin_amdgcn_readlane((int)__float_as_uint(v), i));
}

// ---------------------------------------------------------------- fused setup + fill
// R1/R2-verified structure. R9 change: edge record is one 16B AoS store
// {src, ex, ey, pad} -> ONE random cache line per edge instead of two
// (was 4B into srt_src + 8B into srt_ea, two separate scattered arrays).
//   b<512:        W2 -> B-fragment bf16 hi/lo planes, h' = 2*(h&63)+(h>>6) permuted
//   b<1762:       lin0 + relu
//   b==1762:      gstart binary search
//   b>=1763:      direct-slot edge bucketing (625 blocks)
__global__ void k_setup(const float* __restrict__ w2, unsigned short* __restrict__ w2f,
                        const float* __restrict__ x, const float* __restrict__ lw,
                        const float* __restrict__ lb, float* __restrict__ out,
                        const int* __restrict__ batch, int* __restrict__ gstart,
                        const int* __restrict__ ei, const float* __restrict__ ea,
                        int* __restrict__ cursor,
                        int4* __restrict__ srt) {
    int b = blockIdx.x, t = threadIdx.x;
    if (b < 512) {
        int tid = b * 256 + t;                        // linear w2 index (coalesced)
        int h = tid >> 10, rem = tid & 1023, i = rem >> 5, n = rem & 31;
        float v = w2[tid];
        unsigned short hi = f2bf(v);
        unsigned short lo = f2bf(v - bf2f(hi));
        int hp = 2 * (h & 63) + (h >> 6);             // h' permutation
        int s = hp >> 5, hm = hp & 31, q = hm >> 3, j = hm & 7;
        int tile = n >> 4, nn = n & 15, lane = q * 16 + nn;
        int c = (i * 4 + s) * 2 + tile;
        w2f[(c * 2 + 0) * 512 + lane * 8 + j] = hi;
        w2f[(c * 2 + 1) * 512 + lane * 8 + j] = lo;
    } else if (b < 1762) {
        int idx = (b - 512) * 256 + t;               // < NN*DIM
        int n = idx >> 5, d = idx & 31;
        out[idx] = fmaxf(x[n] * lw[d] + lb[d], 0.f);
    } else if (b == 1762) {
        if (t <= NG) {
            int g = t, lo = 0, hi = NN;
            while (lo < hi) { int mid = (lo + hi) >> 1; if (batch[mid] < g) lo = mid + 1; else hi = mid; }
            gstart[g] = lo;
        }
    } else {
        int e = (b - 1763) * 256 + t;
        if (e < NE) {
            int d = ei[NE + e];
            int p = atomicAdd(&cursor[d], 1);
            float2 a = *(const float2*)(ea + 2 * e);
            int4 rec;
            rec.x = ei[e];
            rec.y = __float_as_int(a.x);
            rec.z = __float_as_int(a.y);
            rec.w = 0;
            srt[d * CAP + p] = rec;                   // single 16B scattered store
        }
    }
}

// ---------------------------------------------------------------- degree-sorted node order
// R1-verified counting sort, DESCENDING. Single block; 16 sub-histograms.
__global__ __launch_bounds__(1024) void k_perm(const int* __restrict__ cursor,
                                               int* __restrict__ perm) {
    __shared__ int hist[NBIN * 16];
    __shared__ int binsum[NBIN];
    __shared__ int base[NBIN];
    int t = threadIdx.x;
    for (int i = t; i < NBIN * 16; i += 1024) hist[i] = 0;
    __syncthreads();
    int sub = t & 15;
    for (int n = t; n < NN; n += 1024) {
        int d = cursor[n]; d = d > CAP ? CAP : d;
        atomicAdd(&hist[d * 16 + sub], 1);
    }
    __syncthreads();
    if (t < NBIN) {
        int s = 0;
        #pragma unroll
        for (int k = 0; k < 16; ++k) s += hist[t * 16 + k];
        binsum[t] = s;
    }
    __syncthreads();
    if (t == 0) {
        int acc = 0;
        for (int d = CAP; d >= 0; --d) { base[d] = acc; acc += binsum[d]; }  // descending
    }
    __syncthreads();
    if (t < NBIN) {                      // exclusive prefix over the 16 sub-counters
        int acc = base[t];
        #pragma unroll
        for (int k = 0; k < 16; ++k) {
            int c = hist[t * 16 + k];
            hist[t * 16 + k] = acc;
            acc += c;
        }
    }
    __syncthreads();
    for (int n = t; n < NN; n += 1024) {
        int d = cursor[n]; d = d > CAP ? CAP : d;
        int pos = atomicAdd(&hist[d * 16 + sub], 1);
        perm[pos] = n;
    }
}

// ---------------------------------------------------------------- NNConv + GRU fused
// R2-verified structure (66.5us, absmax 0.0): 8 waves / 8 nodes / 512 thr;
// pk_fma f32x2 edge accumulation; h'-adjacent packed cvt stores; readlane-
// preloaded edge metadata (now one dwordx4 AoS load); Sg through LDS.
#define NS 1040
#define PS 8320
__global__ __launch_bounds__(512, 4) void k_conv_gru(
    const int* __restrict__ perm,
    const int* __restrict__ cursor, const int4* __restrict__ srt,
    const float* __restrict__ w1, const float* __restrict__ b1,
    const unsigned short* __restrict__ w2f, const float* __restrict__ b2,
    const float* __restrict__ out_old,
    const float* __restrict__ root, const float* __restrict__ cbias,
    const float* __restrict__ wih, const float* __restrict__ whh,
    const float* __restrict__ bih, const float* __restrict__ bhh,
    float* __restrict__ out_new)
{
    __shared__ __align__(16) unsigned short RB[2 * PS];   // hi plane + lo plane
    __shared__ float sSg[8][DIM];
    __shared__ int sNode[8];
    int t = threadIdx.x;
    int wave = t >> 6, lane = t & 63;
    int n0 = blockIdx.x * 8;
    int n = perm[n0 + wave];
    if (lane == 0) sNode[wave] = n;

    // ---------------- edge phase ----------------
    f32x2 acc2[32];                       // .x: h'=2*lane, .y: h'=2*lane+1
    #pragma unroll
    for (int i = 0; i < 32; ++i) acc2[i] = (f32x2){0.f, 0.f};
    float sacc = 0.f;

    float w1a0 = w1[lane],      w1c0 = w1[128 + lane],  bb0 = b1[lane];
    float w1a1 = w1[64 + lane], w1c1 = w1[192 + lane],  bb1 = b1[64 + lane];

    int deg = cursor[n];
    int rs = n * CAP;

    // lane-parallel preload of edge metadata: one dwordx4 per lane
    int msrc = 0; float mex = 0.f, mey = 0.f;
    if (lane < deg) {
        int4 rec = srt[rs + lane];
        msrc = rec.x;
        mex = __int_as_float(rec.y);
        mey = __int_as_float(rec.z);
    }

    int dmain = deg < 64 ? deg : 64;
    int i = 0;
    for (; i + 1 < dmain; i += 2) {
        int s0 = __builtin_amdgcn_readlane(msrc, i);
        int s1 = __builtin_amdgcn_readlane(msrc, i + 1);
        float a0x = rlanef(mex, i),     a0y = rlanef(mey, i);
        float a1x = rlanef(mex, i + 1), a1y = rlanef(mey, i + 1);
        const float* o0 = out_old + s0 * DIM;     // uniform -> s_load
        const float* o1 = out_old + s1 * DIM;     // independent chain
        f32x2 r0 = { fmaxf(a0x * w1a0 + a0y * w1c0 + bb0, 0.f),
                     fmaxf(a0x * w1a1 + a0y * w1c1 + bb1, 0.f) };
        f32x2 r1 = { fmaxf(a1x * w1a0 + a1y * w1c0 + bb0, 0.f),
                     fmaxf(a1x * w1a1 + a1y * w1c1 + bb1, 0.f) };
        #pragma unroll
        for (int q = 0; q < 32; ++q)
            acc2[q] += r0 * o0[q];                // v_pk_fma_f32
        #pragma unroll
        for (int q = 0; q < 32; ++q)
            acc2[q] += r1 * o1[q];
        const float* oc = (lane < 32) ? (o0 + lane) : (o1 + lane - 32);
        sacc += *oc;
    }
    if (i < dmain) {                               // tail edge
        int s0 = __builtin_amdgcn_readlane(msrc, i);
        float a0x = rlanef(mex, i), a0y = rlanef(mey, i);
        const float* o0 = out_old + s0 * DIM;
        f32x2 r0 = { fmaxf(a0x * w1a0 + a0y * w1c0 + bb0, 0.f),
                     fmaxf(a0x * w1a1 + a0y * w1c1 + bb1, 0.f) };
        #pragma unroll
        for (int q = 0; q < 32; ++q)
            acc2[q] += r0 * o0[q];
        if (lane < 32) sacc += o0[lane];
    }
    for (int p = rs + 64; p < rs + deg; ++p) {     // rare fallback deg > 64
        int4 rec = srt[p];                         // uniform address
        int s0 = __builtin_amdgcn_readfirstlane(rec.x);
        float a0x = __int_as_float(rec.y);
        float a0y = __int_as_float(rec.z);
        const float* o0 = out_old + s0 * DIM;
        f32x2 r0 = { fmaxf(a0x * w1a0 + a0y * w1c0 + bb0, 0.f),
                     fmaxf(a0x * w1a1 + a0y * w1c1 + bb1, 0.f) };
        #pragma unroll
        for (int q = 0; q < 32; ++q)
            acc2[q] += r0 * o0[q];
        if (lane < 32) sacc += o0[lane];
    }
    sacc += __shfl_xor(sacc, 32);                  // combine the two row-halves
    if (lane < DIM) sSg[wave][lane] = sacc;

    // ---------------- MFMA contraction: 4 i-passes of 8 ----------------
    int quad = lane >> 4;
    int mm = lane & 7;                  // A rows 8..15 dup of 0..7 (unread in D)
    unsigned aoff = (unsigned)(mm * NS + wave * 128 + quad * 8);
    f32x4 acc0 = {0.f, 0.f, 0.f, 0.f};
    f32x4 acc1 = {0.f, 0.f, 0.f, 0.f};

    unsigned short* Hw = RB + wave * NS;
    unsigned short* Lw = RB + PS + wave * NS;

    #pragma unroll
    for (int pass = 0; pass < 4; ++pass) {
        if (pass) __syncthreads();                 // prior pass's reads done
        #pragma unroll
        for (int li = 0; li < 8; ++li) {
            f32x2 v = acc2[pass * 8 + li];         // h'=2*lane (.x), 2*lane+1 (.y)
            unsigned short h0 = f2bf(v.x);
            unsigned short l0 = f2bf(v.x - bf2f(h0));
            unsigned short h1 = f2bf(v.y);
            unsigned short l1 = f2bf(v.y - bf2f(h1));
            *(unsigned*)(Hw + li * 128 + 2 * lane) = (unsigned)h0 | ((unsigned)h1 << 16);
            *(unsigned*)(Lw + li * 128 + 2 * lane) = (unsigned)l0 | ((unsigned)l1 << 16);
        }
        __syncthreads();
        int ig = pass * 8 + wave;                  // global i-row this wave covers
        #pragma unroll
        for (int s = 0; s < 4; ++s) {
            bf16x8 ah = *(const bf16x8*)(RB + aoff + s * 32);
            bf16x8 al = *(const bf16x8*)(RB + PS + aoff + s * 32);
            const unsigned short* bp = w2f + (unsigned)((ig * 4 + s) * 2048 + lane * 8);
            bf16x8 bh0 = *(const bf16x8*)(bp);
            bf16x8 bl0 = *(const bf16x8*)(bp + 512);
            bf16x8 bh1 = *(const bf16x8*)(bp + 1024);
            bf16x8 bl1 = *(const bf16x8*)(bp + 1536);
            acc0 = __builtin_amdgcn_mfma_f32_16x16x32_bf16(ah, bh0, acc0, 0, 0, 0);
            acc0 = __builtin_amdgcn_mfma_f32_16x16x32_bf16(ah, bl0, acc0, 0, 0, 0);
            acc0 = __builtin_amdgcn_mfma_f32_16x16x32_bf16(al, bh0, acc0, 0, 0, 0);
            acc1 = __builtin_amdgcn_mfma_f32_16x16x32_bf16(ah, bh1, acc1, 0, 0, 0);
            acc1 = __builtin_amdgcn_mfma_f32_16x16x32_bf16(ah, bl1, acc1, 0, 0, 0);
            acc1 = __builtin_amdgcn_mfma_f32_16x16x32_bf16(al, bh1, acc1, 0, 0, 0);
        }
    }
    __syncthreads();                               // all RB reads complete

    // ---- K-partial reduction through LDS (reuse RB as float area) ----
    float* part = (float*)RB;                      // 16 tiles x 64 lanes x 4 = 16 KB
    #pragma unroll
    for (int r = 0; r < 4; ++r) {
        part[((wave * 2 + 0) * 64 + lane) * 4 + r] = acc0[r];
        part[((wave * 2 + 1) * 64 + lane) * 4 + r] = acc1[r];
    }
    __syncthreads();

    // ---------------- fused GRU epilogue (threads 0..255: 8 nodes x 32 dims) ----------------
    if (t < 256) {
        int nb = t >> 5, d = t & 31;
        int nn_ = sNode[nb];
        int base = t & 32;                          // shfl base within wave
        // C/D layout: row=(lane>>4)*4+reg, col=lane&15 -> gather this (nb,d)
        int tile = d >> 4, col = d & 15;
        int lidx = (nb >> 2) * 16 + col, reg = nb & 3;
        float aggv = 0.f;
        #pragma unroll
        for (int wv = 0; wv < 8; ++wv)
            aggv += part[((wv * 2 + tile) * 64 + lidx) * 4 + reg];

        float bt = 0.f;
        #pragma unroll 8
        for (int i2 = 0; i2 < DIM; ++i2) bt += sSg[nb][i2] * b2[i2 * DIM + d];
        int cdeg = cursor[nn_];
        float degf = (float)(cdeg > 0 ? cdeg : 1);
        aggv = (aggv + bt) / degf;

        float x = out_old[nn_ * DIM + d];           // h_old[d]
        float rootsum = 0.f;
        #pragma unroll 8
        for (int k = 0; k < DIM; ++k)
            rootsum += __shfl(x, base + k) * root[k * DIM + d];
        float m = fmaxf(aggv + rootsum + cbias[d], 0.f);

        float gir = bih[d], giz = bih[DIM + d], gin = bih[2 * DIM + d];
        float ghr = bhh[d], ghz = bhh[DIM + d], ghn = bhh[2 * DIM + d];
        #pragma unroll 4
        for (int k = 0; k < DIM; ++k) {
            float mk = __shfl(m, base + k);
            float hk = __shfl(x, base + k);
            gir += mk * wih[k * 96 + d];
            giz += mk * wih[k * 96 + DIM + d];
            gin += mk * wih[k * 96 + 2 * DIM + d];
            ghr += hk * whh[k * 96 + d];
            ghz += hk * whh[k * 96 + DIM + d];
            ghn += hk * whh[k * 96 + 2 * DIM + d];
        }
        float rg = sigmoidf_(gir + ghr);
        float zg = sigmoidf_(giz + ghz);
        float ng = tanhf(gin + rg * ghn);
        out_new[nn_ * DIM + d] = (1.f - zg) * ng + zg * x;
    }
}

// ---------------------------------------------------------------- Set2Set + head (R2-verified)
__global__ __launch_bounds__(256) void k_set2set(
    const float* __restrict__ out, const int* __restrict__ gstart,
    const float* __restrict__ wih, const float* __restrict__ whh,
    const float* __restrict__ bih, const float* __restrict__ bhh,
    const float* __restrict__ l1w, const float* __restrict__ l1b,
    const float* __restrict__ l2w, const float* __restrict__ l2b,
    float* __restrict__ ebuf, float* __restrict__ y)
{
    __shared__ float swih[64 * 128];   // 32 KB
    __shared__ float swhh[32 * 128];   // 16 KB
    __shared__ float sq[2 * DIM];
    __shared__ float shh[DIM], scc[DIM];
    __shared__ float sgates[4 * DIM];
    __shared__ float sacc[8][DIM];
    __shared__ float sredA[4], sredB[4];

    int g = blockIdx.x, t = threadIdx.x;
    {
        const float4* wv = (const float4*)wih;   float4* sv = (float4*)swih;
        for (int i = t; i < 2048; i += 256) sv[i] = wv[i];
        const float4* wv2 = (const float4*)whh;  float4* sv2 = (float4*)swhh;
        for (int i = t; i < 1024; i += 256) sv2[i] = wv2[i];
    }
    if (t < 2 * DIM) sq[t] = 0.f;
    if (t < DIM) { shh[t] = 0.f; scc[t] = 0.f; }
    int ns = gstart[g], ne = gstart[g + 1];
    __syncthreads();

    for (int step = 0; step < 3; ++step) {
        if (t < 128) {
            float acc = bih[t] + bhh[t];
            #pragma unroll 8
            for (int k = 0; k < 2 * DIM; ++k) acc += sq[k] * swih[k * 128 + t];
            #pragma unroll 8
            for (int k = 0; k < DIM; ++k)     acc += shh[k] * swhh[k * 128 + t];
            sgates[t] = acc;
        }
        __syncthreads();
        if (t < DIM) {
            float ig = sigmoidf_(sgates[t]);
            float fg = sigmoidf_(sgates[DIM + t]);
            float gg = tanhf(sgates[2 * DIM + t]);
            float og = sigmoidf_(sgates[3 * DIM + t]);
            float c_new = fg * scc[t] + ig * gg;
            float h_new = og * tanhf(c_new);
            scc[t] = c_new;
            shh[t] = h_new;
            sq[t] = h_new;
        }
        __syncthreads();

        float lmax = -3.0e38f;
        for (int n = ns + t; n < ne; n += 256) {
            const float4* orow = (const float4*)(out + n * DIM);
            float e = 0.f;
            #pragma unroll
            for (int q = 0; q < 8; ++q) {
                float4 o4 = orow[q];
                e += o4.x * shh[4 * q] + o4.y * shh[4 * q + 1]
                   + o4.z * shh[4 * q + 2] + o4.w * shh[4 * q + 3];
            }
            ebuf[n] = e;
            lmax = fmaxf(lmax, e);
        }
        #pragma unroll
        for (int s = 1; s < 64; s <<= 1) lmax = fmaxf(lmax, __shfl_xor(lmax, s));
        if ((t & 63) == 0) sredA[t >> 6] = lmax;
        __syncthreads();
        float M = fmaxf(fmaxf(sredA[0], sredA[1]), fmaxf(sredA[2], sredA[3]));

        float lsum = 0.f;
        for (int n = ns + t; n < ne; n += 256) {
            float v = expf(ebuf[n] - M);
            ebuf[n] = v;
            lsum += v;
        }
        #pragma unroll
        for (int s = 1; s < 64; s <<= 1) lsum += __shfl_xor(lsum, s);
        if ((t & 63) == 0) sredB[t >> 6] = lsum;
        __syncthreads();
        float S = sredB[0] + sredB[1] + sredB[2] + sredB[3];
        float inv = (S > 0.f) ? 1.f / S : 0.f;

        int stp = t >> 5, d = t & 31;
        float racc = 0.f;
        for (int n = ns + stp; n < ne; n += 8)
            racc += ebuf[n] * out[n * DIM + d];
        sacc[stp][d] = racc;
        __syncthreads();
        if (t < DIM) {
            float r = 0.f;
            #pragma unroll
            for (int s = 0; s < 8; ++s) r += sacc[s][t];
            sq[DIM + t] = r * inv;
        }
        __syncthreads();
    }

    if (t < DIM) {
        float h = l1b[t];
        #pragma unroll 8
        for (int k = 0; k < 2 * DIM; ++k) h += sq[k] * l1w[k * DIM + t];
        float v = fmaxf(h, 0.f) * l2w[t];
        #pragma unroll
        for (int s = 1; s < 32; s <<= 1) v += __shfl_xor(v, s);
        if (t == 0) y[g] = v + l2b[0];
    }
}

// ---------------------------------------------------------------- launch
extern "C" void kernel_launch(void* const* d_in, const int* in_sizes, int n_in,
                              void* d_out, int out_size, void* d_ws, size_t ws_size,
                              hipStream_t stream) {
    const float* x         = (const float*)d_in[0];
    const float* edge_attr = (const float*)d_in[1];
    const float* lin0_w    = (const float*)d_in[2];
    const float* lin0_b    = (const float*)d_in[3];
    const float* nn_w1     = (const float*)d_in[4];
    const float* nn_b1     = (const float*)d_in[5];
    const float* nn_w2     = (const float*)d_in[6];
    const float* nn_b2     = (const float*)d_in[7];
    const float* conv_root = (const float*)d_in[8];
    const float* conv_bias = (const float*)d_in[9];
    const float* gru_w_ih  = (const float*)d_in[10];
    const float* gru_w_hh  = (const float*)d_in[11];
    const float* gru_b_ih  = (const float*)d_in[12];
    const float* gru_b_hh  = (const float*)d_in[13];
    const float* lstm_w_ih = (const float*)d_in[14];
    const float* lstm_w_hh = (const float*)d_in[15];
    const float* lstm_b_ih = (const float*)d_in[16];
    const float* lstm_b_hh = (const float*)d_in[17];
    const float* lin1_w    = (const float*)d_in[18];
    const float* lin1_b    = (const float*)d_in[19];
    const float* lin2_w    = (const float*)d_in[20];
    const float* lin2_b    = (const float*)d_in[21];
    const int*   edge_index= (const int*)d_in[22];
    const int*   batch     = (const int*)d_in[23];
    float* yout = (float*)d_out;

    char* p = (char*)d_ws;
    auto alloc = [&](size_t bytes) { char* r = p; p += (bytes + 255) & ~(size_t)255; return r; };

    // ---- zero region (one memset) ----
    int*   cursor = (int*)  alloc(NN * sizeof(int));
    size_t zero_bytes = (size_t)(p - (char*)d_ws);
    // ---- rest ----
    int*   gstart    = (int*)  alloc((NG + 1) * sizeof(int));
    int4*  srt       = (int4*) alloc((size_t)NN * CAP * sizeof(int4));
    float* outA      = (float*)alloc(NN * DIM * sizeof(float));
    float* outB      = (float*)alloc(NN * DIM * sizeof(float));
    int*   perm      = (int*)  alloc(NN * sizeof(int));
    unsigned short* w2f = (unsigned short*)alloc(262144 * sizeof(unsigned short));
    float* ebuf      = (float*)alloc(NN * sizeof(float));
    (void)ws_size; (void)n_in; (void)in_sizes; (void)out_size;

    hipMemsetAsync(d_ws, 0, zero_bytes, stream);

    k_setup<<<2388, 256, 0, stream>>>(nn_w2, w2f, x, lin0_w, lin0_b, outA, batch, gstart,
                                      edge_index, edge_attr, cursor, srt);
    k_perm<<<1, 1024, 0, stream>>>(cursor, perm);

    const float* cur = outA;
    float* nxt = outB;
    for (int it = 0; it < 3; ++it) {
        k_conv_gru<<<1250, 512, 0, stream>>>(perm, cursor, srt,
                                             nn_w1, nn_b1, w2f, nn_b2,
                                             cur,
                                             conv_root, conv_bias,
                                             gru_w_ih, gru_w_hh, gru_b_ih, gru_b_hh,
                                             nxt);
        const float* tmp = nxt; nxt = (float*)cur; cur = tmp;
    }
    const float* outF = cur;

    k_set2set<<<NG, 256, 0, stream>>>(outF, gstart,
                                      lstm_w_ih, lstm_w_hh, lstm_b_ih, lstm_b_hh,
                                      lin1_w, lin1_b, lin2_w, lin2_b, ebuf, yout);
}